// Round 1
// baseline (369.318 us; speedup 1.0000x reference)
//
#include <hip/hip_runtime.h>
#include <hip/hip_bf16.h>

#define D 64

// ---------------------------------------------------------------------------
// out[n*D + d] = bias[d]  (bias broadcast init; scatter accumulates on top)
// ---------------------------------------------------------------------------
__global__ __launch_bounds__(256) void init_kernel(const float* __restrict__ bias,
                                                   float* __restrict__ out,
                                                   int total4) {
    // total4 = (N*D)/4 float4 elements; D==64 so each float4 stays inside one row
    int i = blockIdx.x * 256 + threadIdx.x;
    int stride = gridDim.x * 256;
    for (; i < total4; i += stride) {
        int base = (i * 4) & (D - 1);
        float4 b;
        b.x = bias[base + 0];
        b.y = bias[base + 1];
        b.z = bias[base + 2];
        b.w = bias[base + 3];
        reinterpret_cast<float4*>(out)[i] = b;
    }
}

// ---------------------------------------------------------------------------
// support = x @ (W0 + W1 + W2)   [N,64] @ [64,64]
// One wave per row. Wsum staged in LDS (summed during load). The wave stages
// its x-row in LDS and broadcast-reads x[k] (uniform address) each step;
// Ws[k*64+lane] is stride-1 across lanes -> conflict-free.
// ---------------------------------------------------------------------------
__global__ __launch_bounds__(256) void gemm_kernel(const float* __restrict__ x,
                                                   const float* __restrict__ w0,
                                                   const float* __restrict__ w1,
                                                   const float* __restrict__ w2,
                                                   float* __restrict__ support,
                                                   int n) {
    __shared__ float Ws[D * D];
    __shared__ float xs[4][D];

    for (int i = threadIdx.x; i < D * D; i += 256)
        Ws[i] = w0[i] + w1[i] + w2[i];
    __syncthreads();

    const int wid  = threadIdx.x >> 6;
    const int lane = threadIdx.x & 63;
    int row = blockIdx.x * 4 + wid;
    const int nw = gridDim.x * 4;

    for (; row < n; row += nw) {
        xs[wid][lane] = x[(size_t)row * D + lane];
        // compiler inserts lgkmcnt wait before dependent reads (same wave,
        // same LDS array -> conservative ordering); no __syncthreads needed
        // since each wave only touches its own xs[wid] row.
        float acc = 0.0f;
#pragma unroll
        for (int k = 0; k < D; ++k) {
            acc += xs[wid][k] * Ws[k * D + lane];
        }
        support[(size_t)row * D + lane] = acc;
    }
}

// ---------------------------------------------------------------------------
// COO scatter: out[rows[e]] += vals[e] * support[cols[e]]
// One wave per edge; lane = feature. HW f32 atomics (global_atomic_add_f32).
// ---------------------------------------------------------------------------
__global__ __launch_bounds__(256) void scatter_kernel(const int* __restrict__ rows,
                                                      const int* __restrict__ cols,
                                                      const float* __restrict__ vals,
                                                      const float* __restrict__ support,
                                                      float* __restrict__ out,
                                                      int ne) {
    const int wid  = blockIdx.x * 4 + (threadIdx.x >> 6);
    const int lane = threadIdx.x & 63;
    const int nw = gridDim.x * 4;

    for (int e = wid; e < ne; e += nw) {
        const int r = rows[e];
        const int c = cols[e];
        const float v = vals[e];
        const float s = support[(size_t)c * D + lane];
        unsafeAtomicAdd(&out[(size_t)r * D + lane], v * s);
    }
}

extern "C" void kernel_launch(void* const* d_in, const int* in_sizes, int n_in,
                              void* d_out, int out_size, void* d_ws, size_t ws_size,
                              hipStream_t stream) {
    const float* x         = (const float*)d_in[0];
    const int*   edge_rows = (const int*)d_in[1];
    const int*   edge_cols = (const int*)d_in[2];
    const float* edge_vals = (const float*)d_in[3];
    const float* w_own     = (const float*)d_in[4];
    const float* w_nbr     = (const float*)d_in[5];
    const float* w_temp    = (const float*)d_in[6];
    const float* bias      = (const float*)d_in[7];

    float* out = (float*)d_out;
    float* support = (float*)d_ws;   // N*D floats = 25.6 MB scratch

    const int n_nodes = in_sizes[0] / D;
    const int n_edges = in_sizes[1];

    // 1) out = bias (broadcast)
    {
        int total4 = (n_nodes * D) / 4;
        int blocks = (total4 + 255) / 256;
        if (blocks > 2048) blocks = 2048;
        init_kernel<<<blocks, 256, 0, stream>>>(bias, out, total4);
    }

    // 2) support = x @ (W_own + W_nbr + W_temp)
    {
        int blocks = 1024;  // 4096 waves, grid-stride over 100K rows
        gemm_kernel<<<blocks, 256, 0, stream>>>(x, w_own, w_nbr, w_temp, support, n_nodes);
    }

    // 3) out[r] += v * support[c] over all edges
    {
        int blocks = 2048;  // 8192 waves ~= full residency
        scatter_kernel<<<blocks, 256, 0, stream>>>(edge_rows, edge_cols, edge_vals,
                                                   support, out, n_edges);
    }
}

// Round 2
// 308.771 us; speedup vs baseline: 1.1961x; 1.1961x over previous
//
#include <hip/hip_runtime.h>
#include <hip/hip_bf16.h>

#define D 64
#define SCAN_CHUNK 1024

// ===========================================================================
// Shared: support = x @ (W0+W1+W2)   [N,64]@[64,64]
// ===========================================================================
__global__ __launch_bounds__(256) void gemm_kernel(const float* __restrict__ x,
                                                   const float* __restrict__ w0,
                                                   const float* __restrict__ w1,
                                                   const float* __restrict__ w2,
                                                   float* __restrict__ support,
                                                   int n) {
    __shared__ float Ws[D * D];
    __shared__ float xs[4][D];

    for (int i = threadIdx.x; i < D * D; i += 256)
        Ws[i] = w0[i] + w1[i] + w2[i];
    __syncthreads();

    const int wid  = threadIdx.x >> 6;
    const int lane = threadIdx.x & 63;
    int row = blockIdx.x * 4 + wid;
    const int nw = gridDim.x * 4;

    for (; row < n; row += nw) {
        xs[wid][lane] = x[(size_t)row * D + lane];
        float acc = 0.0f;
#pragma unroll
        for (int k = 0; k < D; ++k) {
            acc += xs[wid][k] * Ws[k * D + lane];
        }
        support[(size_t)row * D + lane] = acc;
    }
}

// ===========================================================================
// CSR build: histogram -> exclusive scan (3 kernels) -> fill (packed int2)
// ===========================================================================
__global__ __launch_bounds__(256) void zero_kernel(int* __restrict__ p, int n) {
    int i = blockIdx.x * 256 + threadIdx.x;
    int stride = gridDim.x * 256;
    for (; i < n; i += stride) p[i] = 0;
}

__global__ __launch_bounds__(256) void hist_kernel(const int* __restrict__ rows,
                                                   int* __restrict__ cnt, int ne) {
    int i = blockIdx.x * 256 + threadIdx.x;
    int stride = gridDim.x * 256;
    for (; i < ne; i += stride) atomicAdd(&cnt[rows[i]], 1);
}

// per-chunk (1024 elems) totals
__global__ __launch_bounds__(256) void scan_partial_kernel(const int* __restrict__ cnt,
                                                           int n, int* __restrict__ bsum) {
    __shared__ int red[256];
    int base = blockIdx.x * SCAN_CHUNK + threadIdx.x * 4;
    int s = 0;
#pragma unroll
    for (int j = 0; j < 4; ++j) { int idx = base + j; if (idx < n) s += cnt[idx]; }
    red[threadIdx.x] = s;
    __syncthreads();
    for (int off = 128; off > 0; off >>= 1) {
        if (threadIdx.x < off) red[threadIdx.x] += red[threadIdx.x + off];
        __syncthreads();
    }
    if (threadIdx.x == 0) bsum[blockIdx.x] = red[0];
}

// exclusive scan of chunk totals (nb <= 1024); also writes rowptr[n] = total
__global__ __launch_bounds__(256) void scan_bsum_kernel(const int* __restrict__ bsum, int nb,
                                                        int* __restrict__ boff,
                                                        int* __restrict__ rowptr, int n) {
    __shared__ int s[1024];
    for (int i = threadIdx.x; i < nb; i += 256) s[i] = bsum[i];
    __syncthreads();
    if (threadIdx.x == 0) {
        int run = 0;
        for (int i = 0; i < nb; ++i) { int t = s[i]; s[i] = run; run += t; }
        rowptr[n] = run;
    }
    __syncthreads();
    for (int i = threadIdx.x; i < nb; i += 256) boff[i] = s[i];
}

// final exclusive prefix into rowptr + working copy woff
__global__ __launch_bounds__(256) void scan_final_kernel(const int* __restrict__ cnt, int n,
                                                         const int* __restrict__ boff,
                                                         int* __restrict__ rowptr,
                                                         int* __restrict__ woff) {
    __shared__ int ts[256];
    const int tid = threadIdx.x;
    int base = blockIdx.x * SCAN_CHUNK + tid * 4;
    int v[4]; int tsum = 0;
#pragma unroll
    for (int j = 0; j < 4; ++j) { int idx = base + j; v[j] = (idx < n) ? cnt[idx] : 0; tsum += v[j]; }
    ts[tid] = tsum;
    __syncthreads();
    // Hillis-Steele inclusive scan over 256 thread-sums
    for (int off = 1; off < 256; off <<= 1) {
        int t = (tid >= off) ? ts[tid - off] : 0;
        __syncthreads();
        ts[tid] += t;
        __syncthreads();
    }
    int excl = ts[tid] - tsum + boff[blockIdx.x];
#pragma unroll
    for (int j = 0; j < 4; ++j) {
        int idx = base + j;
        if (idx < n) { rowptr[idx] = excl; woff[idx] = excl; excl += v[j]; }
    }
}

__global__ __launch_bounds__(256) void csr_fill_kernel(const int* __restrict__ rows,
                                                       const int* __restrict__ cols,
                                                       const float* __restrict__ vals,
                                                       int* __restrict__ woff,
                                                       int2* __restrict__ csr, int ne) {
    int i = blockIdx.x * 256 + threadIdx.x;
    int stride = gridDim.x * 256;
    for (; i < ne; i += stride) {
        int r = rows[i];
        int p = atomicAdd(&woff[r], 1);
        int2 cv; cv.x = cols[i]; cv.y = __float_as_int(vals[i]);
        csr[p] = cv;
    }
}

// ===========================================================================
// Pull: out[r] = bias + sum_j val[j] * support[col[j]]   (no atomics)
// wave per row, lane = feature; 2-way unroll for gather latency overlap
// ===========================================================================
__global__ __launch_bounds__(256) void pull_kernel(const int* __restrict__ rowptr,
                                                   const int2* __restrict__ csr,
                                                   const float* __restrict__ support,
                                                   const float* __restrict__ bias,
                                                   float* __restrict__ out, int n) {
    const int lane = threadIdx.x & 63;
    int w = blockIdx.x * 4 + (threadIdx.x >> 6);
    const int nw = gridDim.x * 4;
    const float b = bias[lane];
    for (int r = w; r < n; r += nw) {
        int jb = rowptr[r], je = rowptr[r + 1];
        float acc0 = 0.0f, acc1 = 0.0f;
        int j = jb;
        for (; j + 1 < je; j += 2) {
            int2 cv0 = csr[j];
            int2 cv1 = csr[j + 1];
            acc0 += __int_as_float(cv0.y) * support[(size_t)cv0.x * D + lane];
            acc1 += __int_as_float(cv1.y) * support[(size_t)cv1.x * D + lane];
        }
        if (j < je) {
            int2 cv = csr[j];
            acc0 += __int_as_float(cv.y) * support[(size_t)cv.x * D + lane];
        }
        out[(size_t)r * D + lane] = acc0 + acc1 + b;
    }
}

// ===========================================================================
// Fallback path (R1, verified): bias-init + atomic scatter — used only if
// ws_size can't hold the CSR workspace.
// ===========================================================================
__global__ __launch_bounds__(256) void init_kernel(const float* __restrict__ bias,
                                                   float* __restrict__ out, int total4) {
    int i = blockIdx.x * 256 + threadIdx.x;
    int stride = gridDim.x * 256;
    for (; i < total4; i += stride) {
        int base = (i * 4) & (D - 1);
        float4 b;
        b.x = bias[base + 0]; b.y = bias[base + 1];
        b.z = bias[base + 2]; b.w = bias[base + 3];
        reinterpret_cast<float4*>(out)[i] = b;
    }
}

__global__ __launch_bounds__(256) void scatter_kernel(const int* __restrict__ rows,
                                                      const int* __restrict__ cols,
                                                      const float* __restrict__ vals,
                                                      const float* __restrict__ support,
                                                      float* __restrict__ out, int ne) {
    const int wid  = blockIdx.x * 4 + (threadIdx.x >> 6);
    const int lane = threadIdx.x & 63;
    const int nw = gridDim.x * 4;
    for (int e = wid; e < ne; e += nw) {
        const int r = rows[e];
        const int c = cols[e];
        const float v = vals[e];
        unsafeAtomicAdd(&out[(size_t)r * D + lane], v * support[(size_t)c * D + lane]);
    }
}

extern "C" void kernel_launch(void* const* d_in, const int* in_sizes, int n_in,
                              void* d_out, int out_size, void* d_ws, size_t ws_size,
                              hipStream_t stream) {
    const float* x         = (const float*)d_in[0];
    const int*   edge_rows = (const int*)d_in[1];
    const int*   edge_cols = (const int*)d_in[2];
    const float* edge_vals = (const float*)d_in[3];
    const float* w_own     = (const float*)d_in[4];
    const float* w_nbr     = (const float*)d_in[5];
    const float* w_temp    = (const float*)d_in[6];
    const float* bias      = (const float*)d_in[7];

    float* out = (float*)d_out;
    const int n_nodes = in_sizes[0] / D;
    const int n_edges = in_sizes[1];
    const int nb = (n_nodes + SCAN_CHUNK - 1) / SCAN_CHUNK;   // prefix-scan chunks

    // ---- workspace layout ----
    char* ws = (char*)d_ws;
    size_t off = 0;
    auto take = [&](size_t bytes) -> char* {
        char* p = ws + off;
        off = (off + bytes + 15) & ~(size_t)15;
        return p;
    };
    float* support = (float*)take((size_t)n_nodes * D * sizeof(float));
    int*   cnt     = (int*)  take((size_t)n_nodes * sizeof(int));
    int*   rowptr  = (int*)  take((size_t)(n_nodes + 1) * sizeof(int));
    int*   woff    = (int*)  take((size_t)n_nodes * sizeof(int));
    int*   bsum    = (int*)  take((size_t)nb * sizeof(int));
    int*   boff    = (int*)  take((size_t)nb * sizeof(int));
    int2*  csr     = (int2*) take((size_t)n_edges * sizeof(int2));
    const bool csr_fits = (off <= ws_size) && (nb <= 1024);

    // support = x @ (W_own + W_nbr + W_temp)
    gemm_kernel<<<1024, 256, 0, stream>>>(x, w_own, w_nbr, w_temp, support, n_nodes);

    if (csr_fits) {
        int zb = (n_nodes + 255) / 256; if (zb > 1024) zb = 1024;
        zero_kernel<<<zb, 256, 0, stream>>>(cnt, n_nodes);
        hist_kernel<<<2048, 256, 0, stream>>>(edge_rows, cnt, n_edges);
        scan_partial_kernel<<<nb, 256, 0, stream>>>(cnt, n_nodes, bsum);
        scan_bsum_kernel<<<1, 256, 0, stream>>>(bsum, nb, boff, rowptr, n_nodes);
        scan_final_kernel<<<nb, 256, 0, stream>>>(cnt, n_nodes, boff, rowptr, woff);
        csr_fill_kernel<<<2048, 256, 0, stream>>>(edge_rows, edge_cols, edge_vals,
                                                  woff, csr, n_edges);
        pull_kernel<<<2048, 256, 0, stream>>>(rowptr, csr, support, bias, out, n_nodes);
    } else {
        int total4 = (n_nodes * D) / 4;
        int blocks = (total4 + 255) / 256; if (blocks > 2048) blocks = 2048;
        init_kernel<<<blocks, 256, 0, stream>>>(bias, out, total4);
        scatter_kernel<<<2048, 256, 0, stream>>>(edge_rows, edge_cols, edge_vals,
                                                 support, out, n_edges);
    }
}